// Round 2
// baseline (1297.357 us; speedup 1.0000x reference)
//
#include <hip/hip_runtime.h>

#define B_N 4096
#define D_N 1024
#define L_N 16384
#define K_N 64
#define CAP 512
#define CNT_STRIDE 16   // one cand counter per 64B cache line

typedef __attribute__((ext_vector_type(8))) short bf16x8;
typedef __attribute__((ext_vector_type(4))) float f32x4;

__device__ __forceinline__ unsigned short f2bf(float f) {
  union { float f; unsigned int u; } v; v.f = f;
  unsigned int r = v.u + 0x7FFFu + ((v.u >> 16) & 1u);
  return (unsigned short)(r >> 16);
}
__device__ __forceinline__ float bf2f(unsigned short u) {
  union { unsigned int u; float f; } v; v.u = (unsigned int)u << 16;
  return v.f;
}

// ---------------- fused prep: W_enc->bf16 | xbar+sigma+cnt0 | W_dec transpose ----------------
// grid = 16384 (wenc) + 4096 (xbar) + 16384 (transpose) = 36864 blocks
__global__ __launch_bounds__(256) void prep_all(const float* __restrict__ x,
                                                const float* __restrict__ W_enc,
                                                const float* __restrict__ W_dec,
                                                const float* __restrict__ b_dec,
                                                unsigned short* __restrict__ wencb,
                                                unsigned short* __restrict__ xbarb,
                                                float* __restrict__ srow,
                                                unsigned short* __restrict__ WdTb,
                                                int* __restrict__ cand_cnt) {
  __shared__ float tile[32][33];
  __shared__ float wsum[4];
  const int t = threadIdx.x;
  const int bid = blockIdx.x;
  if (bid < 16384) {                       // W_enc fp32 -> bf16
    size_t i = (size_t)bid * 256 + t;
    float4 v = ((const float4*)W_enc)[i];
    ushort4 o;
    o.x = f2bf(v.x); o.y = f2bf(v.y); o.z = f2bf(v.z); o.w = f2bf(v.w);
    ((ushort4*)wencb)[i] = o;
  } else if (bid < 20480) {                // xbar bf16 + per-row sigma + cnt zero
    const int b = bid - 16384;
    if (t == 0) cand_cnt[b * CNT_STRIDE] = 0;
    float4 v = ((const float4*)x)[(size_t)b * 256 + t];
    float4 bd = ((const float4*)b_dec)[t];
    float4 e = make_float4(v.x - bd.x, v.y - bd.y, v.z - bd.z, v.w - bd.w);
    ushort4 o;
    o.x = f2bf(e.x); o.y = f2bf(e.y); o.z = f2bf(e.z); o.w = f2bf(e.w);
    ((ushort4*)xbarb)[(size_t)b * 256 + t] = o;
    float ss = e.x * e.x + e.y * e.y + e.z * e.z + e.w * e.w;
#pragma unroll
    for (int off = 32; off; off >>= 1) ss += __shfl_down(ss, off);
    if ((t & 63) == 0) wsum[t >> 6] = ss;
    __syncthreads();
    if (t == 0) srow[b] = sqrtf((wsum[0] + wsum[1] + wsum[2] + wsum[3]) * (1.0f / D_N));
  } else {                                 // W_dec [D][L] -> W_decT bf16 [L][D]
    const int tb = bid - 20480;
    const int l0 = (tb & 511) * 32;        // L/32 = 512
    const int d0 = (tb >> 9) * 32;
    const int tx = t & 31, ty = t >> 5;
    for (int i = ty; i < 32; i += 8)
      tile[i][tx] = W_dec[(size_t)(d0 + i) * L_N + l0 + tx];
    __syncthreads();
    for (int i = ty; i < 32; i += 8)
      WdTb[(size_t)(l0 + i) * D_N + d0 + tx] = f2bf(tile[tx][i]);
  }
}

// ---------------- encoder GEMM 256x256, BK=64, 8 waves, SINGLE-buffer 64KB LDS ----------------
// Regime: 2 blocks/CU (16 waves) -> implicit inter-block overlap absorbs the
// per-K-tile stage drain (m97/m114 mechanism), on top of 256^2's better
// LDS-read:MFMA ratio (24 ds_read_b128 per 64 MFMA) and the zero-conflict
// both-sides XOR swizzle (verified: SQ_LDS_BANK_CONFLICT == 0). Plain 2-phase
// schedule, compiler-scheduled waits. T1 XCD swizzle kept (1024 % 8 == 0).
// Epilogue: bias + 2.3*sigma candidate append + f-tile zero (same accumulation
// order as previous passing kernels -> identical C values).
__global__ __launch_bounds__(512, 4) void gemm_enc_select(
    const unsigned short* __restrict__ A,   // xbar bf16 [B][D]
    const unsigned short* __restrict__ Bw,  // W_enc bf16 [L][D]
    const float* __restrict__ b_enc,
    const float* __restrict__ srow,
    int* __restrict__ cand_cnt,             // [B] stride CNT_STRIDE
    float* __restrict__ cand_val,           // [B][CAP]
    int* __restrict__ cand_idx,             // [B][CAP]
    float* __restrict__ f) {                // [B][L] zeroed here (tile-local)
  __shared__ __align__(16) char smem[65536];   // A tile [256][64]bf16 @0, B @32768
  const int tid = threadIdx.x;
  const int wid = tid >> 6, lane = tid & 63;
  const int wm = wid >> 2, wn = wid & 3;    // 2 x 4 wave grid
  const int fr = lane & 15, quad = lane >> 4;

  // bijective XCD swizzle: 1024 blocks, 1024 % 8 == 0
  const int wg = ((blockIdx.x & 7) << 7) + (blockIdx.x >> 3);
  const int bm = wg & 15, bn = wg >> 4;     // 16 x 64 tiles

  // staging geometry: instr r covers LDS rows r*64 + wid*8 + (lane>>3);
  // lane&7 selects the 16B unit in the 128B row; source col pre-swizzled
  // (unit ^= row&7) so linear LDS dest + swizzled ds_read match (rule #21).
  const int stgrow = wid * 8 + (lane >> 3);
  const int scol = ((lane & 7) ^ (lane >> 3)) << 4;
  const char* gA = (const char*)A + ((size_t)(bm * 256 + stgrow) * D_N) * 2 + scol;
  const char* gB = (const char*)Bw + ((size_t)(bn * 256 + stgrow) * D_N) * 2 + scol;

  f32x4 acc[8][4];
#pragma unroll
  for (int i = 0; i < 8; ++i)
#pragma unroll
    for (int j = 0; j < 4; ++j) acc[i][j] = (f32x4){0.f, 0.f, 0.f, 0.f};

  // per-lane ds_read bases (byte offsets); row stride 128B
  const int aB = (wm * 128 + fr) * 128;
  const int bB = 32768 + (wn * 64 + fr) * 128;
  const int s0 = (quad ^ (fr & 7)) << 4;   // swizzled 16B unit for ks=0; ks=1 is ^64

  for (int kt = 0; kt < D_N / 64; ++kt) {
    __syncthreads();   // prior-iter LDS reads done before overwrite
    const size_t ko = (size_t)kt * 128;
#pragma unroll
    for (int r = 0; r < 4; ++r) {
      __builtin_amdgcn_global_load_lds(
          (const __attribute__((address_space(1))) void*)(gA + (size_t)r * 131072 + ko),
          (__attribute__((address_space(3))) void*)(smem + r * 8192 + wid * 1024),
          16, 0, 0);
      __builtin_amdgcn_global_load_lds(
          (const __attribute__((address_space(1))) void*)(gB + (size_t)r * 131072 + ko),
          (__attribute__((address_space(3))) void*)(smem + 32768 + r * 8192 + wid * 1024),
          16, 0, 0);
    }
    __syncthreads();   // vmcnt(0)+lgkmcnt(0) drain -> LDS tile valid

#pragma unroll
    for (int ks = 0; ks < 2; ++ks) {
      bf16x8 af[8], bv[4];
#pragma unroll
      for (int i = 0; i < 8; ++i)
        af[i] = *(const bf16x8*)(smem + aB + i * 2048 + (s0 ^ (ks * 64)));
#pragma unroll
      for (int j = 0; j < 4; ++j)
        bv[j] = *(const bf16x8*)(smem + bB + j * 2048 + (s0 ^ (ks * 64)));
#pragma unroll
      for (int i = 0; i < 8; ++i)
#pragma unroll
        for (int j = 0; j < 4; ++j)
          acc[i][j] = __builtin_amdgcn_mfma_f32_16x16x32_bf16(af[i], bv[j], acc[i][j], 0, 0, 0);
    }
  }

  // epilogue: D layout col=lane&15, row=quad*4+reg  [m89-verified]
  const int lc0 = bn * 256 + wn * 64 + fr;
  float be[4];
#pragma unroll
  for (int nj = 0; nj < 4; ++nj) be[nj] = b_enc[lc0 + nj * 16];
  const int gr0 = bm * 256 + wm * 128 + quad * 4;
#pragma unroll
  for (int mi = 0; mi < 8; ++mi) {
#pragma unroll
    for (int r = 0; r < 4; ++r) {
      const int grow = gr0 + mi * 16 + r;
      const float thr = 2.3f * srow[grow];
#pragma unroll
      for (int nj = 0; nj < 4; ++nj) {
        const float val = acc[mi][nj][r] + be[nj];
        if (val > thr) {
          const int p = atomicAdd(&cand_cnt[grow * CNT_STRIDE], 1);
          if (p < CAP) {
            cand_val[(size_t)grow * CAP + p] = val;
            cand_idx[(size_t)grow * CAP + p] = lc0 + nj * 16;
          }
        }
      }
    }
  }

  // zero this block's 256x256 f tile LAST — fire-and-forget streaming stores
  {
    const float4 z4 = make_float4(0.f, 0.f, 0.f, 0.f);
    float4* fz = (float4*)(f + (size_t)(bm * 256) * L_N + bn * 256);
#pragma unroll
    for (int it = 0; it < 32; ++it) {
      const int idx = it * 512 + tid;          // 0..16383 float4 slots
      const int rr = idx >> 6, cc = idx & 63;  // 64 float4 per tile row
      fz[(size_t)rr * (L_N / 4) + cc] = z4;
    }
  }
}

// ---------------- select + fp64 refine + scatter f + fused decode ----------------
__global__ __launch_bounds__(256) void select_decode(
    const float* __restrict__ x,
    const float* __restrict__ W_enc,
    const float* __restrict__ b_enc,
    const float* __restrict__ b_dec,
    const float* __restrict__ srow,
    const int* __restrict__ cand_cnt,
    const float* __restrict__ cand_val,
    const int* __restrict__ cand_idx,
    const unsigned short* __restrict__ WdTb,
    float* __restrict__ f,
    float* __restrict__ xhat) {
  const int b = blockIdx.x, t = threadIdx.x;
  const int lane = t & 63, wave = t >> 6;
  __shared__ double xd[D_N];       // exact xbar in fp64
  __shared__ float cv[CAP];
  __shared__ int ci[CAP];
  __shared__ double bu[128];       // boundary fp64 scores
  __shared__ int bidx[128];        // boundary slot -> cand slot
  __shared__ int o_idx[K_N];
  __shared__ float o_val[K_N];
  __shared__ int sidx[K_N];
  __shared__ float sval[K_N];
  __shared__ int nb_s, nin_s, outcnt;
  __shared__ float v64_s;

  const int cnt = min(cand_cnt[b * CNT_STRIDE], CAP);
  if (t == 0) { nb_s = 0; nin_s = 0; outcnt = 0; v64_s = -1e30f; }
  for (int c = t; c < cnt; c += 256) {
    cv[c] = cand_val[(size_t)b * CAP + c];
    ci[c] = cand_idx[(size_t)b * CAP + c];
  }
  for (int i = t; i < D_N; i += 256)
    xd[i] = (double)x[(size_t)b * D_N + i] - (double)b_dec[i];
  __syncthreads();

  // v64 = 64th-largest approx value (unique by (val, idx) lexicographic)
  for (int c = t; c < cnt; c += 256) {
    const float v = cv[c];
    const int id = ci[c];
    int r = 0;
    for (int k = 0; k < cnt; ++k)
      r += (cv[k] > v || (cv[k] == v && ci[k] < id)) ? 1 : 0;
    if (r == 63) v64_s = v;   // unique writer
  }
  __syncthreads();
  const float v64 = v64_s;
  const float m = 0.04f * srow[b];

  // classify: definite-in (v > v64+m), boundary (|v - v64| <= m)
  for (int c = t; c < cnt; c += 256) {
    const float v = cv[c];
    if (v > v64 + m) {
      atomicAdd(&nin_s, 1);
    } else if (v >= v64 - m) {
      const int p = atomicAdd(&nb_s, 1);
      if (p < 128) bidx[p] = c;
    }
  }
  __syncthreads();
  const int nb = min(nb_s, 128);
  const int nin = nin_s;
  int nneed = K_N - nin;
  if (nneed < 0) nneed = 0;

  // fp64 exact scores for boundary candidates (one wave per candidate)
  for (int c = wave; c < nb; c += 4) {
    const int l = ci[bidx[c]];
    const float4* wr = (const float4*)(W_enc + (size_t)l * D_N);
    double acc = 0.0;
#pragma unroll
    for (int j = 0; j < 4; ++j) {
      float4 w4 = wr[j * 64 + lane];
      const int base = (j * 64 + lane) * 4;
      acc += xd[base + 0] * (double)w4.x + xd[base + 1] * (double)w4.y +
             xd[base + 2] * (double)w4.z + xd[base + 3] * (double)w4.w;
    }
#pragma unroll
    for (int off = 32; off; off >>= 1) acc += __shfl_down(acc, off);
    if (lane == 0) bu[c] = acc + (double)b_enc[l];
  }
  __syncthreads();

  // emit definite-ins with approx values
  for (int c = t; c < cnt; c += 256) {
    if (cv[c] > v64 + m) {
      const int p = atomicAdd(&outcnt, 1);
      if (p < K_N) { o_idx[p] = ci[c]; o_val[p] = cv[c]; }
    }
  }
  // emit best nneed boundary candidates by exact fp64 score
  if (t < nb) {
    const double uv = bu[t];
    const int l = ci[bidx[t]];
    int r = 0;
    for (int k = 0; k < nb; ++k)
      r += (bu[k] > uv || (bu[k] == uv && ci[bidx[k]] < l)) ? 1 : 0;
    if (r < nneed) {
      const int p = atomicAdd(&outcnt, 1);
      if (p < K_N) { o_idx[p] = l; o_val[p] = (float)uv; }
    }
  }
  __syncthreads();
  const int ns = min(outcnt, K_N);

  if (t < K_N) {
    sidx[t] = (t < ns) ? o_idx[t] : t;
    sval[t] = (t < ns) ? fmaxf(o_val[t], 0.0f) : 0.0f;
  }
  __syncthreads();

  // scatter into f (tile already zeroed by gemm)
  if (t < ns) f[(size_t)b * L_N + sidx[t]] = sval[t];

  // fused decode: xhat row = sum_k sval[k] * W_decT[sidx[k],:] + b_dec
  float4 acc = ((const float4*)b_dec)[t];   // 256 float4 == D_N
#pragma unroll 8
  for (int k = 0; k < K_N; ++k) {
    const float v = sval[k];
    const ushort4 w = ((const ushort4*)(WdTb + (size_t)sidx[k] * D_N))[t];
    acc.x += v * bf2f(w.x); acc.y += v * bf2f(w.y);
    acc.z += v * bf2f(w.z); acc.w += v * bf2f(w.w);
  }
  ((float4*)(xhat + (size_t)b * D_N))[t] = acc;
}

extern "C" void kernel_launch(void* const* d_in, const int* in_sizes, int n_in,
                              void* d_out, int out_size, void* d_ws, size_t ws_size,
                              hipStream_t stream) {
  (void)in_sizes; (void)n_in; (void)out_size; (void)ws_size;
  const float* x     = (const float*)d_in[0];   // [B][D]
  const float* W_enc = (const float*)d_in[1];   // [L][D]
  const float* b_enc = (const float*)d_in[2];   // [L]
  const float* W_dec = (const float*)d_in[3];   // [D][L]
  const float* b_dec = (const float*)d_in[4];   // [D]

  float* f    = (float*)d_out;                        // [B][L]
  float* xhat = (float*)d_out + (size_t)B_N * L_N;    // [B][D]

  // workspace layout (~92 MB total)
  char* ws = (char*)d_ws;
  unsigned short* wencb = (unsigned short*)ws;                   // 32 MB bf16 W_enc
  unsigned short* xbarb = (unsigned short*)(ws + 33554432);      //  8 MB bf16 xbar
  unsigned short* WdTb  = (unsigned short*)(ws + 41943040);      // 32 MB bf16 W_dec^T
  float* srow           = (float*)(ws + 75497472);               // 16 KB
  int* cand_cnt         = (int*)(ws + 75513856);                 // 256 KB (line-padded)
  float* cand_val       = (float*)(ws + 75776000);               //  8 MB
  int* cand_idx         = (int*)(ws + 84164608);                 //  8 MB

  prep_all<<<36864, 256, 0, stream>>>(x, W_enc, W_dec, b_dec, wencb, xbarb, srow,
                                      WdTb, cand_cnt);
  gemm_enc_select<<<1024, 512, 0, stream>>>(
      xbarb, wencb, b_enc, srow, cand_cnt, cand_val, cand_idx, f);
  select_decode<<<B_N, 256, 0, stream>>>(x, W_enc, b_enc, b_dec, srow,
                                         cand_cnt, cand_val, cand_idx, WdTb, f, xhat);
}

// Round 3
// 812.579 us; speedup vs baseline: 1.5966x; 1.5966x over previous
//
#include <hip/hip_runtime.h>

#define B_N 4096
#define D_N 1024
#define L_N 16384
#define K_N 64
#define CAP 512
#define CNT_STRIDE 16   // one cand counter per 64B cache line

typedef __attribute__((ext_vector_type(8))) short bf16x8;
typedef __attribute__((ext_vector_type(4))) float f32x4;

__device__ __forceinline__ unsigned short f2bf(float f) {
  union { float f; unsigned int u; } v; v.f = f;
  unsigned int r = v.u + 0x7FFFu + ((v.u >> 16) & 1u);
  return (unsigned short)(r >> 16);
}
__device__ __forceinline__ float bf2f(unsigned short u) {
  union { unsigned int u; float f; } v; v.u = (unsigned int)u << 16;
  return v.f;
}

// ---------------- fused prep: W_enc->bf16 | xbar+sigma+cnt0 | W_dec transpose ----------------
// grid = 16384 (wenc) + 4096 (xbar) + 16384 (transpose) = 36864 blocks
__global__ __launch_bounds__(256) void prep_all(const float* __restrict__ x,
                                                const float* __restrict__ W_enc,
                                                const float* __restrict__ W_dec,
                                                const float* __restrict__ b_dec,
                                                unsigned short* __restrict__ wencb,
                                                unsigned short* __restrict__ xbarb,
                                                float* __restrict__ srow,
                                                unsigned short* __restrict__ WdTb,
                                                int* __restrict__ cand_cnt) {
  __shared__ float tile[32][33];
  __shared__ float wsum[4];
  const int t = threadIdx.x;
  const int bid = blockIdx.x;
  if (bid < 16384) {                       // W_enc fp32 -> bf16
    size_t i = (size_t)bid * 256 + t;
    float4 v = ((const float4*)W_enc)[i];
    ushort4 o;
    o.x = f2bf(v.x); o.y = f2bf(v.y); o.z = f2bf(v.z); o.w = f2bf(v.w);
    ((ushort4*)wencb)[i] = o;
  } else if (bid < 20480) {                // xbar bf16 + per-row sigma + cnt zero
    const int b = bid - 16384;
    if (t == 0) cand_cnt[b * CNT_STRIDE] = 0;
    float4 v = ((const float4*)x)[(size_t)b * 256 + t];
    float4 bd = ((const float4*)b_dec)[t];
    float4 e = make_float4(v.x - bd.x, v.y - bd.y, v.z - bd.z, v.w - bd.w);
    ushort4 o;
    o.x = f2bf(e.x); o.y = f2bf(e.y); o.z = f2bf(e.z); o.w = f2bf(e.w);
    ((ushort4*)xbarb)[(size_t)b * 256 + t] = o;
    float ss = e.x * e.x + e.y * e.y + e.z * e.z + e.w * e.w;
#pragma unroll
    for (int off = 32; off; off >>= 1) ss += __shfl_down(ss, off);
    if ((t & 63) == 0) wsum[t >> 6] = ss;
    __syncthreads();
    if (t == 0) srow[b] = sqrtf((wsum[0] + wsum[1] + wsum[2] + wsum[3]) * (1.0f / D_N));
  } else {                                 // W_dec [D][L] -> W_decT bf16 [L][D]
    const int tb = bid - 20480;
    const int l0 = (tb & 511) * 32;        // L/32 = 512
    const int d0 = (tb >> 9) * 32;
    const int tx = t & 31, ty = t >> 5;
    for (int i = ty; i < 32; i += 8)
      tile[i][tx] = W_dec[(size_t)(d0 + i) * L_N + l0 + tx];
    __syncthreads();
    for (int i = ty; i < 32; i += 8)
      WdTb[(size_t)(l0 + i) * D_N + d0 + tx] = f2bf(tile[tx][i]);
  }
}

// ---------------- encoder GEMM 256x256, BK=64, 8 waves, dbuf 128KB, 2-phase ----------------
// T3 "minimum 2-phase" recipe (m248: 655-666 TF @ 256^2 K=1024):
//   STAGE(next tile -> other buffer); unbroken compute region (24 ds_read_b128 +
//   64 MFMA, compiler-scheduled fine-grained lgkmcnt); ONE __syncthreads per
//   K-tile (its vmcnt(0) waits only on loads a full compute-phase old -> free).
// No inline barriers / setprio / sched_barrier (R1 post-mortem: they lockstep the
// waves and defeat the compiler's ds_read<->MFMA pipeline, m141 lesson).
// launch_bounds(512,2): VGPR cap 256 -> no spill (R2 post-mortem: min-waves=4
// capped at 128 < acc's 128+overhead -> 2.3GB scratch traffic).
// Both-sides XOR swizzle kept (verified: SQ_LDS_BANK_CONFLICT == 0).
// Epilogue unchanged (same accumulation order -> identical outputs).
__global__ __launch_bounds__(512, 2) void gemm_enc_select(
    const unsigned short* __restrict__ A,   // xbar bf16 [B][D]
    const unsigned short* __restrict__ Bw,  // W_enc bf16 [L][D]
    const float* __restrict__ b_enc,
    const float* __restrict__ srow,
    int* __restrict__ cand_cnt,             // [B] stride CNT_STRIDE
    float* __restrict__ cand_val,           // [B][CAP]
    int* __restrict__ cand_idx,             // [B][CAP]
    float* __restrict__ f) {                // [B][L] zeroed here (tile-local)
  __shared__ __align__(16) char smem[131072];  // buf p @ p*65536: A[256][64] @0, B @32768
  const int tid = threadIdx.x;
  const int wid = tid >> 6, lane = tid & 63;
  const int wm = wid >> 2, wn = wid & 3;    // 2 x 4 wave grid
  const int fr = lane & 15, quad = lane >> 4;

  // bijective XCD swizzle: 1024 blocks, 1024 % 8 == 0
  const int wg = ((blockIdx.x & 7) << 7) + (blockIdx.x >> 3);
  const int bm = wg & 15, bn = wg >> 4;     // 16 x 64 tiles

  // staging geometry: instr r covers LDS rows r*64 + wid*8 + (lane>>3);
  // lane&7 selects the 16B unit in the 128B row; source col pre-swizzled
  // (unit ^= row&7) so linear LDS dest + swizzled ds_read match (rule #21).
  const int stgrow = wid * 8 + (lane >> 3);
  const int scol = ((lane & 7) ^ (lane >> 3)) << 4;
  const char* gA = (const char*)A + ((size_t)(bm * 256 + stgrow) * D_N) * 2 + scol;
  const char* gB = (const char*)Bw + ((size_t)(bn * 256 + stgrow) * D_N) * 2 + scol;

#define STAGE(kt_, p_)                                                                     \
  {                                                                                        \
    const size_t ko_ = (size_t)(kt_)*128;                                                  \
    _Pragma("unroll") for (int r_ = 0; r_ < 4; ++r_) {                                     \
      __builtin_amdgcn_global_load_lds(                                                    \
          (const __attribute__((address_space(1))) void*)(gA + (size_t)r_ * 131072 + ko_), \
          (__attribute__((address_space(3))) void*)(smem + (p_) * 65536 + r_ * 8192 + wid * 1024), \
          16, 0, 0);                                                                       \
      __builtin_amdgcn_global_load_lds(                                                    \
          (const __attribute__((address_space(1))) void*)(gB + (size_t)r_ * 131072 + ko_), \
          (__attribute__((address_space(3))) void*)(smem + (p_) * 65536 + 32768 + r_ * 8192 + wid * 1024), \
          16, 0, 0);                                                                       \
    }                                                                                      \
  }

  f32x4 acc[8][4];
#pragma unroll
  for (int i = 0; i < 8; ++i)
#pragma unroll
    for (int j = 0; j < 4; ++j) acc[i][j] = (f32x4){0.f, 0.f, 0.f, 0.f};

  // per-lane ds_read bases (byte offsets); row stride 128B
  const int aB = (wm * 128 + fr) * 128;
  const int bB = 32768 + (wn * 64 + fr) * 128;
  const int s0 = (quad ^ (fr & 7)) << 4;   // swizzled 16B unit for ks=0; ks=1 is ^64

  STAGE(0, 0);
  __syncthreads();   // vmcnt(0) drain + barrier -> buf0 valid

  for (int kt = 0; kt < D_N / 64; ++kt) {
    const int pb = (kt & 1) * 65536;
    if (kt < D_N / 64 - 1) STAGE(kt + 1, (kt & 1) ^ 1);

    // unbroken compute region: compiler interleaves ds_reads with MFMAs
#pragma unroll
    for (int ks = 0; ks < 2; ++ks) {
      bf16x8 af[8], bv[4];
#pragma unroll
      for (int i = 0; i < 8; ++i)
        af[i] = *(const bf16x8*)(smem + pb + aB + i * 2048 + (s0 ^ (ks * 64)));
#pragma unroll
      for (int j = 0; j < 4; ++j)
        bv[j] = *(const bf16x8*)(smem + pb + bB + j * 2048 + (s0 ^ (ks * 64)));
#pragma unroll
      for (int i = 0; i < 8; ++i)
#pragma unroll
        for (int j = 0; j < 4; ++j)
          acc[i][j] = __builtin_amdgcn_mfma_f32_16x16x32_bf16(af[i], bv[j], acc[i][j], 0, 0, 0);
    }

    __syncthreads();   // vmcnt(0): next-tile loads are ~one compute-phase old; barrier
  }

  // epilogue: D layout col=lane&15, row=quad*4+reg  [m89-verified]
  const int lc0 = bn * 256 + wn * 64 + fr;
  float be[4];
#pragma unroll
  for (int nj = 0; nj < 4; ++nj) be[nj] = b_enc[lc0 + nj * 16];
  const int gr0 = bm * 256 + wm * 128 + quad * 4;
#pragma unroll
  for (int mi = 0; mi < 8; ++mi) {
#pragma unroll
    for (int r = 0; r < 4; ++r) {
      const int grow = gr0 + mi * 16 + r;
      const float thr = 2.3f * srow[grow];
#pragma unroll
      for (int nj = 0; nj < 4; ++nj) {
        const float val = acc[mi][nj][r] + be[nj];
        if (val > thr) {
          const int p = atomicAdd(&cand_cnt[grow * CNT_STRIDE], 1);
          if (p < CAP) {
            cand_val[(size_t)grow * CAP + p] = val;
            cand_idx[(size_t)grow * CAP + p] = lc0 + nj * 16;
          }
        }
      }
    }
  }

  // zero this block's 256x256 f tile LAST — fire-and-forget streaming stores
  {
    const float4 z4 = make_float4(0.f, 0.f, 0.f, 0.f);
    float4* fz = (float4*)(f + (size_t)(bm * 256) * L_N + bn * 256);
#pragma unroll
    for (int it = 0; it < 32; ++it) {
      const int idx = it * 512 + tid;          // 0..16383 float4 slots
      const int rr = idx >> 6, cc = idx & 63;  // 64 float4 per tile row
      fz[(size_t)rr * (L_N / 4) + cc] = z4;
    }
  }
#undef STAGE
}

// ---------------- select + fp64 refine + scatter f + fused decode ----------------
__global__ __launch_bounds__(256) void select_decode(
    const float* __restrict__ x,
    const float* __restrict__ W_enc,
    const float* __restrict__ b_enc,
    const float* __restrict__ b_dec,
    const float* __restrict__ srow,
    const int* __restrict__ cand_cnt,
    const float* __restrict__ cand_val,
    const int* __restrict__ cand_idx,
    const unsigned short* __restrict__ WdTb,
    float* __restrict__ f,
    float* __restrict__ xhat) {
  const int b = blockIdx.x, t = threadIdx.x;
  const int lane = t & 63, wave = t >> 6;
  __shared__ double xd[D_N];       // exact xbar in fp64
  __shared__ float cv[CAP];
  __shared__ int ci[CAP];
  __shared__ double bu[128];       // boundary fp64 scores
  __shared__ int bidx[128];        // boundary slot -> cand slot
  __shared__ int o_idx[K_N];
  __shared__ float o_val[K_N];
  __shared__ int sidx[K_N];
  __shared__ float sval[K_N];
  __shared__ int nb_s, nin_s, outcnt;
  __shared__ float v64_s;

  const int cnt = min(cand_cnt[b * CNT_STRIDE], CAP);
  if (t == 0) { nb_s = 0; nin_s = 0; outcnt = 0; v64_s = -1e30f; }
  for (int c = t; c < cnt; c += 256) {
    cv[c] = cand_val[(size_t)b * CAP + c];
    ci[c] = cand_idx[(size_t)b * CAP + c];
  }
  for (int i = t; i < D_N; i += 256)
    xd[i] = (double)x[(size_t)b * D_N + i] - (double)b_dec[i];
  __syncthreads();

  // v64 = 64th-largest approx value (unique by (val, idx) lexicographic)
  for (int c = t; c < cnt; c += 256) {
    const float v = cv[c];
    const int id = ci[c];
    int r = 0;
    for (int k = 0; k < cnt; ++k)
      r += (cv[k] > v || (cv[k] == v && ci[k] < id)) ? 1 : 0;
    if (r == 63) v64_s = v;   // unique writer
  }
  __syncthreads();
  const float v64 = v64_s;
  const float m = 0.04f * srow[b];

  // classify: definite-in (v > v64+m), boundary (|v - v64| <= m)
  for (int c = t; c < cnt; c += 256) {
    const float v = cv[c];
    if (v > v64 + m) {
      atomicAdd(&nin_s, 1);
    } else if (v >= v64 - m) {
      const int p = atomicAdd(&nb_s, 1);
      if (p < 128) bidx[p] = c;
    }
  }
  __syncthreads();
  const int nb = min(nb_s, 128);
  const int nin = nin_s;
  int nneed = K_N - nin;
  if (nneed < 0) nneed = 0;

  // fp64 exact scores for boundary candidates (one wave per candidate)
  for (int c = wave; c < nb; c += 4) {
    const int l = ci[bidx[c]];
    const float4* wr = (const float4*)(W_enc + (size_t)l * D_N);
    double acc = 0.0;
#pragma unroll
    for (int j = 0; j < 4; ++j) {
      float4 w4 = wr[j * 64 + lane];
      const int base = (j * 64 + lane) * 4;
      acc += xd[base + 0] * (double)w4.x + xd[base + 1] * (double)w4.y +
             xd[base + 2] * (double)w4.z + xd[base + 3] * (double)w4.w;
    }
#pragma unroll
    for (int off = 32; off; off >>= 1) acc += __shfl_down(acc, off);
    if (lane == 0) bu[c] = acc + (double)b_enc[l];
  }
  __syncthreads();

  // emit definite-ins with approx values
  for (int c = t; c < cnt; c += 256) {
    if (cv[c] > v64 + m) {
      const int p = atomicAdd(&outcnt, 1);
      if (p < K_N) { o_idx[p] = ci[c]; o_val[p] = cv[c]; }
    }
  }
  // emit best nneed boundary candidates by exact fp64 score
  if (t < nb) {
    const double uv = bu[t];
    const int l = ci[bidx[t]];
    int r = 0;
    for (int k = 0; k < nb; ++k)
      r += (bu[k] > uv || (bu[k] == uv && ci[bidx[k]] < l)) ? 1 : 0;
    if (r < nneed) {
      const int p = atomicAdd(&outcnt, 1);
      if (p < K_N) { o_idx[p] = l; o_val[p] = (float)uv; }
    }
  }
  __syncthreads();
  const int ns = min(outcnt, K_N);

  if (t < K_N) {
    sidx[t] = (t < ns) ? o_idx[t] : t;
    sval[t] = (t < ns) ? fmaxf(o_val[t], 0.0f) : 0.0f;
  }
  __syncthreads();

  // scatter into f (tile already zeroed by gemm)
  if (t < ns) f[(size_t)b * L_N + sidx[t]] = sval[t];

  // fused decode: xhat row = sum_k sval[k] * W_decT[sidx[k],:] + b_dec
  float4 acc = ((const float4*)b_dec)[t];   // 256 float4 == D_N
#pragma unroll 8
  for (int k = 0; k < K_N; ++k) {
    const float v = sval[k];
    const ushort4 w = ((const ushort4*)(WdTb + (size_t)sidx[k] * D_N))[t];
    acc.x += v * bf2f(w.x); acc.y += v * bf2f(w.y);
    acc.z += v * bf2f(w.z); acc.w += v * bf2f(w.w);
  }
  ((float4*)(xhat + (size_t)b * D_N))[t] = acc;
}

extern "C" void kernel_launch(void* const* d_in, const int* in_sizes, int n_in,
                              void* d_out, int out_size, void* d_ws, size_t ws_size,
                              hipStream_t stream) {
  (void)in_sizes; (void)n_in; (void)out_size; (void)ws_size;
  const float* x     = (const float*)d_in[0];   // [B][D]
  const float* W_enc = (const float*)d_in[1];   // [L][D]
  const float* b_enc = (const float*)d_in[2];   // [L]
  const float* W_dec = (const float*)d_in[3];   // [D][L]
  const float* b_dec = (const float*)d_in[4];   // [D]

  float* f    = (float*)d_out;                        // [B][L]
  float* xhat = (float*)d_out + (size_t)B_N * L_N;    // [B][D]

  // workspace layout (~92 MB total)
  char* ws = (char*)d_ws;
  unsigned short* wencb = (unsigned short*)ws;                   // 32 MB bf16 W_enc
  unsigned short* xbarb = (unsigned short*)(ws + 33554432);      //  8 MB bf16 xbar
  unsigned short* WdTb  = (unsigned short*)(ws + 41943040);      // 32 MB bf16 W_dec^T
  float* srow           = (float*)(ws + 75497472);               // 16 KB
  int* cand_cnt         = (int*)(ws + 75513856);                 // 256 KB (line-padded)
  float* cand_val       = (float*)(ws + 75776000);               //  8 MB
  int* cand_idx         = (int*)(ws + 84164608);                 //  8 MB

  prep_all<<<36864, 256, 0, stream>>>(x, W_enc, W_dec, b_dec, wencb, xbarb, srow,
                                      WdTb, cand_cnt);
  gemm_enc_select<<<1024, 512, 0, stream>>>(
      xbarb, wencb, b_enc, srow, cand_cnt, cand_val, cand_idx, f);
  select_decode<<<B_N, 256, 0, stream>>>(x, W_enc, b_enc, b_dec, srow,
                                         cand_cnt, cand_val, cand_idx, WdTb, f, xhat);
}

// Round 4
// 803.732 us; speedup vs baseline: 1.6142x; 1.0110x over previous
//
#include <hip/hip_runtime.h>

#define B_N 4096
#define D_N 1024
#define L_N 16384
#define K_N 64
#define CAP 512
#define CNT_STRIDE 16   // one cand counter per 64B cache line

typedef __attribute__((ext_vector_type(8))) short bf16x8;
typedef __attribute__((ext_vector_type(4))) float f32x4;

__device__ __forceinline__ unsigned short f2bf(float f) {
  union { float f; unsigned int u; } v; v.f = f;
  unsigned int r = v.u + 0x7FFFu + ((v.u >> 16) & 1u);
  return (unsigned short)(r >> 16);
}
__device__ __forceinline__ float bf2f(unsigned short u) {
  union { unsigned int u; float f; } v; v.u = (unsigned int)u << 16;
  return v.f;
}

// ---------------- fused prep: W_enc->bf16 | xbar+sigma+cnt0 | W_dec transpose ----------------
// grid = 16384 (wenc) + 4096 (xbar) + 16384 (transpose) = 36864 blocks
__global__ __launch_bounds__(256) void prep_all(const float* __restrict__ x,
                                                const float* __restrict__ W_enc,
                                                const float* __restrict__ W_dec,
                                                const float* __restrict__ b_dec,
                                                unsigned short* __restrict__ wencb,
                                                unsigned short* __restrict__ xbarb,
                                                float* __restrict__ srow,
                                                unsigned short* __restrict__ WdTb,
                                                int* __restrict__ cand_cnt) {
  __shared__ float tile[32][33];
  __shared__ float wsum[4];
  const int t = threadIdx.x;
  const int bid = blockIdx.x;
  if (bid < 16384) {                       // W_enc fp32 -> bf16
    size_t i = (size_t)bid * 256 + t;
    float4 v = ((const float4*)W_enc)[i];
    ushort4 o;
    o.x = f2bf(v.x); o.y = f2bf(v.y); o.z = f2bf(v.z); o.w = f2bf(v.w);
    ((ushort4*)wencb)[i] = o;
  } else if (bid < 20480) {                // xbar bf16 + per-row sigma + cnt zero
    const int b = bid - 16384;
    if (t == 0) cand_cnt[b * CNT_STRIDE] = 0;
    float4 v = ((const float4*)x)[(size_t)b * 256 + t];
    float4 bd = ((const float4*)b_dec)[t];
    float4 e = make_float4(v.x - bd.x, v.y - bd.y, v.z - bd.z, v.w - bd.w);
    ushort4 o;
    o.x = f2bf(e.x); o.y = f2bf(e.y); o.z = f2bf(e.z); o.w = f2bf(e.w);
    ((ushort4*)xbarb)[(size_t)b * 256 + t] = o;
    float ss = e.x * e.x + e.y * e.y + e.z * e.z + e.w * e.w;
#pragma unroll
    for (int off = 32; off; off >>= 1) ss += __shfl_down(ss, off);
    if ((t & 63) == 0) wsum[t >> 6] = ss;
    __syncthreads();
    if (t == 0) srow[b] = sqrtf((wsum[0] + wsum[1] + wsum[2] + wsum[3]) * (1.0f / D_N));
  } else {                                 // W_dec [D][L] -> W_decT bf16 [L][D]
    const int tb = bid - 20480;
    const int l0 = (tb & 511) * 32;        // L/32 = 512
    const int d0 = (tb >> 9) * 32;
    const int tx = t & 31, ty = t >> 5;
    for (int i = ty; i < 32; i += 8)
      tile[i][tx] = W_dec[(size_t)(d0 + i) * L_N + l0 + tx];
    __syncthreads();
    for (int i = ty; i < 32; i += 8)
      WdTb[(size_t)(l0 + i) * D_N + d0 + tx] = f2bf(tile[tx][i]);
  }
}

// ---------------- encoder GEMM 256x256, BK=64, 8 waves, dbuf 128KB, 4-phase counted-vmcnt ----
// Faithful m201/T3+T4 port (R1/R3 post-mortems: drain-0 ~= 1-phase, m218):
//  - waves remapped: wave owns 64 rows in EACH row-half -> phase (rh,ks) reads only A-half rh
//  - stage spread 1 unit (2 gload_lds) per phase, FIFO per tile: B0,B1,A0,A1
//  - counted waits: vmcnt(4) before P2 (A-half1, age ~3 phases), vmcnt(2) at tile
//    boundary (B+A-half0, ages 2-4 phases). NEVER 0 in main loop; last tile peeled.
//  - per-phase: {8 ds_read | 2 stage -> barrier -> lgkmcnt(0)+sched_barrier(0) ->
//    setprio(1) 16 MFMA setprio(0) -> [vmcnt(N)] -> barrier}   (rule #18 honored)
// Swizzle (conflict-free, verified 0) and per-element K-order unchanged -> identical results.
__global__ __launch_bounds__(512, 2) void gemm_enc_select(
    const unsigned short* __restrict__ A,   // xbar bf16 [B][D]
    const unsigned short* __restrict__ Bw,  // W_enc bf16 [L][D]
    const float* __restrict__ b_enc,
    const float* __restrict__ srow,
    int* __restrict__ cand_cnt,             // [B] stride CNT_STRIDE
    float* __restrict__ cand_val,           // [B][CAP]
    int* __restrict__ cand_idx,             // [B][CAP]
    float* __restrict__ f) {                // [B][L] zeroed here (tile-local)
  __shared__ __align__(16) char smem[131072];  // buf p @ p*65536: A[256][64] @0, B @32768
  const int tid = threadIdx.x;
  const int wid = tid >> 6, lane = tid & 63;
  const int wm = wid >> 2, wn = wid & 3;    // 2 x 4 wave grid
  const int fr = lane & 15, quad = lane >> 4;

  // bijective XCD swizzle: 1024 blocks, 1024 % 8 == 0
  const int wg = ((blockIdx.x & 7) << 7) + (blockIdx.x >> 3);
  const int bm = wg & 15, bn = wg >> 4;     // 16 x 64 tiles

  // staging geometry: instr r covers LDS rows r*64 + wid*8 + (lane>>3);
  // lane&7 = 16B unit in the 128B row; source unit pre-swizzled (^= row&7).
  const int stgrow = wid * 8 + (lane >> 3);
  const int scol = ((lane & 7) ^ (lane >> 3)) << 4;
  const char* gA = (const char*)A + ((size_t)(bm * 256 + stgrow) * D_N) * 2 + scol;
  const char* gB = (const char*)Bw + ((size_t)(bn * 256 + stgrow) * D_N) * 2 + scol;

// one stage unit = 2 gload_lds instrs = 128 rows of one matrix
#define STG(gsrc_, doff_, r0_, po_, ko_)                                                   \
  _Pragma("unroll") for (int r_ = (r0_); r_ < (r0_) + 2; ++r_) {                           \
    __builtin_amdgcn_global_load_lds(                                                      \
        (const __attribute__((address_space(1))) void*)((gsrc_) + (size_t)r_ * 131072 + (ko_)), \
        (__attribute__((address_space(3))) void*)(smem + (po_) + (doff_) + r_ * 8192 + wid * 1024), \
        16, 0, 0);                                                                         \
  }

#define DSRD(rh_, ks_)                                                                     \
  bf16x8 af[4], bv[4];                                                                     \
  _Pragma("unroll") for (int i_ = 0; i_ < 4; ++i_)                                         \
      af[i_] = *(const bf16x8*)(smem + pb + (rh_)*16384 + aB + i_ * 2048 + (s0 ^ ((ks_)*64))); \
  _Pragma("unroll") for (int j_ = 0; j_ < 4; ++j_)                                         \
      bv[j_] = *(const bf16x8*)(smem + pb + bB + j_ * 2048 + (s0 ^ ((ks_)*64)));

#define MFMA16(rh_)                                                                        \
  __builtin_amdgcn_s_setprio(1);                                                           \
  _Pragma("unroll") for (int i_ = 0; i_ < 4; ++i_)                                         \
      _Pragma("unroll") for (int j_ = 0; j_ < 4; ++j_)                                     \
          acc[(rh_)*4 + i_][j_] = __builtin_amdgcn_mfma_f32_16x16x32_bf16(                 \
              af[i_], bv[j_], acc[(rh_)*4 + i_][j_], 0, 0, 0);                             \
  __builtin_amdgcn_s_setprio(0);

#define BAR __builtin_amdgcn_s_barrier()
#define LGKM0                                                                              \
  do {                                                                                     \
    asm volatile("s_waitcnt lgkmcnt(0)" ::: "memory");                                     \
    __builtin_amdgcn_sched_barrier(0);                                                     \
  } while (0)
#define VMW(n_) asm volatile("s_waitcnt vmcnt(" #n_ ")" ::: "memory")

  f32x4 acc[8][4];
#pragma unroll
  for (int i = 0; i < 8; ++i)
#pragma unroll
    for (int j = 0; j < 4; ++j) acc[i][j] = (f32x4){0.f, 0.f, 0.f, 0.f};

  // per-lane ds_read bases (byte offsets); row stride 128B.
  // wave's A rows: half rh -> rh*128 + wm*64 + i*16 + fr  (64 rows per half)
  const int aB = (wm * 64 + fr) * 128;
  const int bB = 32768 + (wn * 64 + fr) * 128;
  const int s0 = (quad ^ (fr & 7)) << 4;   // swizzled 16B unit for ks=0; ks=1 is ^64

  // prologue: stage tile 0, FIFO order B0,B1,A0,A1; allow A1 outstanding
  STG(gB, 32768, 0, 0, (size_t)0)
  STG(gB, 32768, 2, 0, (size_t)0)
  STG(gA, 0, 0, 0, (size_t)0)
  STG(gA, 0, 2, 0, (size_t)0)
  VMW(2);
  BAR;

  for (int kt = 0; kt < 15; ++kt) {
    const int pb = (kt & 1) * 65536;
    const int po = pb ^ 65536;
    const size_t ko = (size_t)(kt + 1) * 128;
    { DSRD(0, 0) STG(gB, 32768, 0, po, ko) BAR; LGKM0; MFMA16(0) BAR; }
    { DSRD(0, 1) STG(gB, 32768, 2, po, ko) BAR; LGKM0; MFMA16(0) VMW(4); BAR; }
    { DSRD(1, 0) STG(gA, 0, 0, po, ko) BAR; LGKM0; MFMA16(1) BAR; }
    { DSRD(1, 1) STG(gA, 0, 2, po, ko) BAR; LGKM0; MFMA16(1) VMW(2); BAR; }
  }
  {  // kt = 15 peeled: no staging; drain A1(15) before P2
    const int pb = 65536;
    { DSRD(0, 0) BAR; LGKM0; MFMA16(0) BAR; }
    { DSRD(0, 1) BAR; LGKM0; MFMA16(0) VMW(0); BAR; }
    { DSRD(1, 0) BAR; LGKM0; MFMA16(1) BAR; }
    { DSRD(1, 1) BAR; LGKM0; MFMA16(1) }
  }

  // epilogue: D layout col=lane&15, row=quad*4+reg  [m89-verified]
  // remapped rows: acc[mi] -> grow = bm*256 + (mi>>2)*128 + wm*64 + (mi&3)*16 + quad*4 + r
  const int lc0 = bn * 256 + wn * 64 + fr;
  float be[4];
#pragma unroll
  for (int nj = 0; nj < 4; ++nj) be[nj] = b_enc[lc0 + nj * 16];
#pragma unroll
  for (int mi = 0; mi < 8; ++mi) {
#pragma unroll
    for (int r = 0; r < 4; ++r) {
      const int grow = bm * 256 + (mi >> 2) * 128 + wm * 64 + (mi & 3) * 16 + quad * 4 + r;
      const float thr = 2.3f * srow[grow];
#pragma unroll
      for (int nj = 0; nj < 4; ++nj) {
        const float val = acc[mi][nj][r] + be[nj];
        if (val > thr) {
          const int p = atomicAdd(&cand_cnt[grow * CNT_STRIDE], 1);
          if (p < CAP) {
            cand_val[(size_t)grow * CAP + p] = val;
            cand_idx[(size_t)grow * CAP + p] = lc0 + nj * 16;
          }
        }
      }
    }
  }

  // zero this block's 256x256 f tile LAST — fire-and-forget streaming stores
  {
    const float4 z4 = make_float4(0.f, 0.f, 0.f, 0.f);
    float4* fz = (float4*)(f + (size_t)(bm * 256) * L_N + bn * 256);
#pragma unroll
    for (int it = 0; it < 32; ++it) {
      const int idx = it * 512 + tid;          // 0..16383 float4 slots
      const int rr = idx >> 6, cc = idx & 63;  // 64 float4 per tile row
      fz[(size_t)rr * (L_N / 4) + cc] = z4;
    }
  }
#undef STG
#undef DSRD
#undef MFMA16
#undef BAR
#undef LGKM0
#undef VMW
}

// ---------------- select + fp64 refine + scatter f + fused decode ----------------
__global__ __launch_bounds__(256) void select_decode(
    const float* __restrict__ x,
    const float* __restrict__ W_enc,
    const float* __restrict__ b_enc,
    const float* __restrict__ b_dec,
    const float* __restrict__ srow,
    const int* __restrict__ cand_cnt,
    const float* __restrict__ cand_val,
    const int* __restrict__ cand_idx,
    const unsigned short* __restrict__ WdTb,
    float* __restrict__ f,
    float* __restrict__ xhat) {
  const int b = blockIdx.x, t = threadIdx.x;
  const int lane = t & 63, wave = t >> 6;
  __shared__ double xd[D_N];       // exact xbar in fp64
  __shared__ float cv[CAP];
  __shared__ int ci[CAP];
  __shared__ double bu[128];       // boundary fp64 scores
  __shared__ int bidx[128];        // boundary slot -> cand slot
  __shared__ int o_idx[K_N];
  __shared__ float o_val[K_N];
  __shared__ int sidx[K_N];
  __shared__ float sval[K_N];
  __shared__ int nb_s, nin_s, outcnt;
  __shared__ float v64_s;

  const int cnt = min(cand_cnt[b * CNT_STRIDE], CAP);
  if (t == 0) { nb_s = 0; nin_s = 0; outcnt = 0; v64_s = -1e30f; }
  for (int c = t; c < cnt; c += 256) {
    cv[c] = cand_val[(size_t)b * CAP + c];
    ci[c] = cand_idx[(size_t)b * CAP + c];
  }
  for (int i = t; i < D_N; i += 256)
    xd[i] = (double)x[(size_t)b * D_N + i] - (double)b_dec[i];
  __syncthreads();

  // v64 = 64th-largest approx value (unique by (val, idx) lexicographic)
  for (int c = t; c < cnt; c += 256) {
    const float v = cv[c];
    const int id = ci[c];
    int r = 0;
    for (int k = 0; k < cnt; ++k)
      r += (cv[k] > v || (cv[k] == v && ci[k] < id)) ? 1 : 0;
    if (r == 63) v64_s = v;   // unique writer
  }
  __syncthreads();
  const float v64 = v64_s;
  const float m = 0.04f * srow[b];

  // classify: definite-in (v > v64+m), boundary (|v - v64| <= m)
  for (int c = t; c < cnt; c += 256) {
    const float v = cv[c];
    if (v > v64 + m) {
      atomicAdd(&nin_s, 1);
    } else if (v >= v64 - m) {
      const int p = atomicAdd(&nb_s, 1);
      if (p < 128) bidx[p] = c;
    }
  }
  __syncthreads();
  const int nb = min(nb_s, 128);
  const int nin = nin_s;
  int nneed = K_N - nin;
  if (nneed < 0) nneed = 0;

  // fp64 exact scores for boundary candidates (one wave per candidate)
  for (int c = wave; c < nb; c += 4) {
    const int l = ci[bidx[c]];
    const float4* wr = (const float4*)(W_enc + (size_t)l * D_N);
    double acc = 0.0;
#pragma unroll
    for (int j = 0; j < 4; ++j) {
      float4 w4 = wr[j * 64 + lane];
      const int base = (j * 64 + lane) * 4;
      acc += xd[base + 0] * (double)w4.x + xd[base + 1] * (double)w4.y +
             xd[base + 2] * (double)w4.z + xd[base + 3] * (double)w4.w;
    }
#pragma unroll
    for (int off = 32; off; off >>= 1) acc += __shfl_down(acc, off);
    if (lane == 0) bu[c] = acc + (double)b_enc[l];
  }
  __syncthreads();

  // emit definite-ins with approx values
  for (int c = t; c < cnt; c += 256) {
    if (cv[c] > v64 + m) {
      const int p = atomicAdd(&outcnt, 1);
      if (p < K_N) { o_idx[p] = ci[c]; o_val[p] = cv[c]; }
    }
  }
  // emit best nneed boundary candidates by exact fp64 score
  if (t < nb) {
    const double uv = bu[t];
    const int l = ci[bidx[t]];
    int r = 0;
    for (int k = 0; k < nb; ++k)
      r += (bu[k] > uv || (bu[k] == uv && ci[bidx[k]] < l)) ? 1 : 0;
    if (r < nneed) {
      const int p = atomicAdd(&outcnt, 1);
      if (p < K_N) { o_idx[p] = l; o_val[p] = (float)uv; }
    }
  }
  __syncthreads();
  const int ns = min(outcnt, K_N);

  if (t < K_N) {
    sidx[t] = (t < ns) ? o_idx[t] : t;
    sval[t] = (t < ns) ? fmaxf(o_val[t], 0.0f) : 0.0f;
  }
  __syncthreads();

  // scatter into f (tile already zeroed by gemm)
  if (t < ns) f[(size_t)b * L_N + sidx[t]] = sval[t];

  // fused decode: xhat row = sum_k sval[k] * W_decT[sidx[k],:] + b_dec
  float4 acc = ((const float4*)b_dec)[t];   // 256 float4 == D_N
#pragma unroll 8
  for (int k = 0; k < K_N; ++k) {
    const float v = sval[k];
    const ushort4 w = ((const ushort4*)(WdTb + (size_t)sidx[k] * D_N))[t];
    acc.x += v * bf2f(w.x); acc.y += v * bf2f(w.y);
    acc.z += v * bf2f(w.z); acc.w += v * bf2f(w.w);
  }
  ((float4*)(xhat + (size_t)b * D_N))[t] = acc;
}

extern "C" void kernel_launch(void* const* d_in, const int* in_sizes, int n_in,
                              void* d_out, int out_size, void* d_ws, size_t ws_size,
                              hipStream_t stream) {
  (void)in_sizes; (void)n_in; (void)out_size; (void)ws_size;
  const float* x     = (const float*)d_in[0];   // [B][D]
  const float* W_enc = (const float*)d_in[1];   // [L][D]
  const float* b_enc = (const float*)d_in[2];   // [L]
  const float* W_dec = (const float*)d_in[3];   // [D][L]
  const float* b_dec = (const float*)d_in[4];   // [D]

  float* f    = (float*)d_out;                        // [B][L]
  float* xhat = (float*)d_out + (size_t)B_N * L_N;    // [B][D]

  // workspace layout (~92 MB total)
  char* ws = (char*)d_ws;
  unsigned short* wencb = (unsigned short*)ws;                   // 32 MB bf16 W_enc
  unsigned short* xbarb = (unsigned short*)(ws + 33554432);      //  8 MB bf16 xbar
  unsigned short* WdTb  = (unsigned short*)(ws + 41943040);      // 32 MB bf16 W_dec^T
  float* srow           = (float*)(ws + 75497472);               // 16 KB
  int* cand_cnt         = (int*)(ws + 75513856);                 // 256 KB (line-padded)
  float* cand_val       = (float*)(ws + 75776000);               //  8 MB
  int* cand_idx         = (int*)(ws + 84164608);                 //  8 MB

  prep_all<<<36864, 256, 0, stream>>>(x, W_enc, W_dec, b_dec, wencb, xbarb, srow,
                                      WdTb, cand_cnt);
  gemm_enc_select<<<1024, 512, 0, stream>>>(
      xbarb, wencb, b_enc, srow, cand_cnt, cand_val, cand_idx, f);
  select_decode<<<B_N, 256, 0, stream>>>(x, W_enc, b_enc, b_dec, srow,
                                         cand_cnt, cand_val, cand_idx, WdTb, f, xhat);
}

// Round 5
// 796.382 us; speedup vs baseline: 1.6291x; 1.0092x over previous
//
#include <hip/hip_runtime.h>

#define B_N 4096
#define D_N 1024
#define L_N 16384
#define K_N 64
#define CAP 512
#define CNT_STRIDE 16   // one cand counter per 64B cache line

typedef __attribute__((ext_vector_type(8))) short bf16x8;
typedef __attribute__((ext_vector_type(4))) float f32x4;

__device__ __forceinline__ unsigned short f2bf(float f) {
  union { float f; unsigned int u; } v; v.f = f;
  unsigned int r = v.u + 0x7FFFu + ((v.u >> 16) & 1u);
  return (unsigned short)(r >> 16);
}
__device__ __forceinline__ float bf2f(unsigned short u) {
  union { unsigned int u; float f; } v; v.u = (unsigned int)u << 16;
  return v.f;
}

// ---------------- fused prep: W_enc->bf16 | xbar+sigma+cnt0 | W_dec transpose ----------------
// grid = 16384 (wenc) + 4096 (xbar) + 16384 (transpose) = 36864 blocks
__global__ __launch_bounds__(256) void prep_all(const float* __restrict__ x,
                                                const float* __restrict__ W_enc,
                                                const float* __restrict__ W_dec,
                                                const float* __restrict__ b_dec,
                                                unsigned short* __restrict__ wencb,
                                                unsigned short* __restrict__ xbarb,
                                                float* __restrict__ srow,
                                                unsigned short* __restrict__ WdTb,
                                                int* __restrict__ cand_cnt) {
  __shared__ float tile[32][33];
  __shared__ float wsum[4];
  const int t = threadIdx.x;
  const int bid = blockIdx.x;
  if (bid < 16384) {                       // W_enc fp32 -> bf16
    size_t i = (size_t)bid * 256 + t;
    float4 v = ((const float4*)W_enc)[i];
    ushort4 o;
    o.x = f2bf(v.x); o.y = f2bf(v.y); o.z = f2bf(v.z); o.w = f2bf(v.w);
    ((ushort4*)wencb)[i] = o;
  } else if (bid < 20480) {                // xbar bf16 + per-row sigma + cnt zero
    const int b = bid - 16384;
    if (t == 0) cand_cnt[b * CNT_STRIDE] = 0;
    float4 v = ((const float4*)x)[(size_t)b * 256 + t];
    float4 bd = ((const float4*)b_dec)[t];
    float4 e = make_float4(v.x - bd.x, v.y - bd.y, v.z - bd.z, v.w - bd.w);
    ushort4 o;
    o.x = f2bf(e.x); o.y = f2bf(e.y); o.z = f2bf(e.z); o.w = f2bf(e.w);
    ((ushort4*)xbarb)[(size_t)b * 256 + t] = o;
    float ss = e.x * e.x + e.y * e.y + e.z * e.z + e.w * e.w;
#pragma unroll
    for (int off = 32; off; off >>= 1) ss += __shfl_down(ss, off);
    if ((t & 63) == 0) wsum[t >> 6] = ss;
    __syncthreads();
    if (t == 0) srow[b] = sqrtf((wsum[0] + wsum[1] + wsum[2] + wsum[3]) * (1.0f / D_N));
  } else {                                 // W_dec [D][L] -> W_decT bf16 [L][D]
    const int tb = bid - 20480;
    const int l0 = (tb & 511) * 32;        // L/32 = 512
    const int d0 = (tb >> 9) * 32;
    const int tx = t & 31, ty = t >> 5;
    for (int i = ty; i < 32; i += 8)
      tile[i][tx] = W_dec[(size_t)(d0 + i) * L_N + l0 + tx];
    __syncthreads();
    for (int i = ty; i < 32; i += 8)
      WdTb[(size_t)(l0 + i) * D_N + d0 + tx] = f2bf(tile[tx][i]);
  }
}

// ---------------- encoder GEMM 256x256, BK=64, 8 waves, dbuf 128KB, deep counted-vmcnt ----
// R4 post-mortem: R4's VMW(2)/VMW(4) waited on loads issued 0-2 phases earlier
// (FIFO miscount) -> each wait exposed ~full memory latency. Fix: issue ALL 8
// loads of tile t+1 in phase 1 of tile t. Waits become:
//   p2: VMW(8)  -> drains A1 of CURRENT buffer (issued 5 phases ago, free)
//   p3: VMW(2)  -> drains B+A0 of next buffer (issued 2 phases ago)
// Last tile peeled with VMW(0) at p2. B fragments cached across row-half phases
// (bv0/bv1): 24 ds_read/wave/tile instead of 32. Swizzle (conflict-free,
// verified 0) and per-element K-order unchanged -> identical results.
// f-tile zero REMOVED (moved to select_decode): cuts 256 MB writes + the
// per-block end-of-kernel store-drain gating the CU's next block.
__global__ __launch_bounds__(512, 2) void gemm_enc_select(
    const unsigned short* __restrict__ A,   // xbar bf16 [B][D]
    const unsigned short* __restrict__ Bw,  // W_enc bf16 [L][D]
    const float* __restrict__ b_enc,
    const float* __restrict__ srow,
    int* __restrict__ cand_cnt,             // [B] stride CNT_STRIDE
    float* __restrict__ cand_val,           // [B][CAP]
    int* __restrict__ cand_idx) {           // [B][CAP]
  __shared__ __align__(16) char smem[131072];  // buf p @ p*65536: A[256][64] @0, B @32768
  const int tid = threadIdx.x;
  const int wid = tid >> 6, lane = tid & 63;
  const int wm = wid >> 2, wn = wid & 3;    // 2 x 4 wave grid
  const int fr = lane & 15, quad = lane >> 4;

  // bijective XCD swizzle: 1024 blocks, 1024 % 8 == 0
  const int wg = ((blockIdx.x & 7) << 7) + (blockIdx.x >> 3);
  const int bm = wg & 15, bn = wg >> 4;     // 16 x 64 tiles

  // staging geometry: instr r covers LDS rows r*64 + wid*8 + (lane>>3);
  // lane&7 = 16B unit in the 128B row; source unit pre-swizzled (^= row&7).
  const int stgrow = wid * 8 + (lane >> 3);
  const int scol = ((lane & 7) ^ (lane >> 3)) << 4;
  const char* gA = (const char*)A + ((size_t)(bm * 256 + stgrow) * D_N) * 2 + scol;
  const char* gB = (const char*)Bw + ((size_t)(bn * 256 + stgrow) * D_N) * 2 + scol;

#define GLD(src_, dst_)                                                   \
  __builtin_amdgcn_global_load_lds(                                       \
      (const __attribute__((address_space(1))) void*)(src_),              \
      (__attribute__((address_space(3))) void*)(dst_), 16, 0, 0)

// stage whole tile kt_ into buffer at byte offset po_. FIFO: B r0..r3, A r0..r3.
// A r0,r1 = rows 0-127 (half0); A r2,r3 = rows 128-255 (half1) -> last 2 instrs = A1.
#define STGALL(po_, ko_)                                                              \
  {                                                                                   \
    _Pragma("unroll") for (int r_ = 0; r_ < 4; ++r_)                                  \
        GLD(gB + (size_t)r_ * 131072 + (ko_), smem + (po_) + 32768 + r_ * 8192 + wid * 1024); \
    _Pragma("unroll") for (int r_ = 0; r_ < 4; ++r_)                                  \
        GLD(gA + (size_t)r_ * 131072 + (ko_), smem + (po_) + r_ * 8192 + wid * 1024); \
  }

#define LDA(rh_, ks_)                                                                 \
  _Pragma("unroll") for (int i_ = 0; i_ < 4; ++i_)                                    \
      af[i_] = *(const bf16x8*)(smem + pb + (rh_)*16384 + aB + i_ * 2048 + (s0 ^ ((ks_)*64)));

#define LDB(dst_, ks_)                                                                \
  _Pragma("unroll") for (int j_ = 0; j_ < 4; ++j_)                                    \
      dst_[j_] = *(const bf16x8*)(smem + pb + bB + j_ * 2048 + (s0 ^ ((ks_)*64)));

#define MFMA16(rh_, bv_)                                                              \
  __builtin_amdgcn_s_setprio(1);                                                      \
  _Pragma("unroll") for (int i_ = 0; i_ < 4; ++i_)                                    \
      _Pragma("unroll") for (int j_ = 0; j_ < 4; ++j_)                                \
          acc[(rh_)*4 + i_][j_] = __builtin_amdgcn_mfma_f32_16x16x32_bf16(            \
              af[i_], bv_[j_], acc[(rh_)*4 + i_][j_], 0, 0, 0);                       \
  __builtin_amdgcn_s_setprio(0);

#define BAR __builtin_amdgcn_s_barrier()
#define LGKM0                                                                         \
  do {                                                                                \
    asm volatile("s_waitcnt lgkmcnt(0)" ::: "memory");                                \
    __builtin_amdgcn_sched_barrier(0);                                                \
  } while (0)
#define VMW(n_) asm volatile("s_waitcnt vmcnt(" #n_ ")" ::: "memory")

  f32x4 acc[8][4];
#pragma unroll
  for (int i = 0; i < 8; ++i)
#pragma unroll
    for (int j = 0; j < 4; ++j) acc[i][j] = (f32x4){0.f, 0.f, 0.f, 0.f};

  // per-lane ds_read bases (byte offsets); row stride 128B.
  // wave's A rows: half rh -> rh*128 + wm*64 + i*16 + fr
  const int aB = (wm * 64 + fr) * 128;
  const int bB = 32768 + (wn * 64 + fr) * 128;
  const int s0 = (quad ^ (fr & 7)) << 4;   // swizzled 16B unit for ks=0; ks=1 is ^64

  // prologue: stage tile 0; drain B+A0 (leave A1 in flight, drained at p2's VMW)
  STGALL(0, (size_t)0)
  VMW(2);
  BAR;

  for (int kt = 0; kt < 15; ++kt) {
    const int pb = (kt & 1) * 65536;
    const int po = pb ^ 65536;
    const size_t ko = (size_t)(kt + 1) * 128;
    bf16x8 af[4], bv0[4], bv1[4];
    // p1: read (A-half0, ks0) + B(ks0); issue ALL of tile kt+1
    LDA(0, 0) LDB(bv0, 0) STGALL(po, ko) BAR; LGKM0; MFMA16(0, bv0) BAR;
    // p2: read (A-half0, ks1) + B(ks1); drain current-buffer A1 (age 5 phases)
    LDA(0, 1) LDB(bv1, 1) BAR; LGKM0; MFMA16(0, bv1) VMW(8); BAR;
    // p3: read (A-half1, ks0), reuse bv0; drain next buffer B+A0 (age 2 phases)
    LDA(1, 0) BAR; LGKM0; MFMA16(1, bv0) VMW(2); BAR;
    // p4: read (A-half1, ks1), reuse bv1
    LDA(1, 1) BAR; LGKM0; MFMA16(1, bv1) BAR;
  }
  {  // kt = 15 peeled: no staging; p2 drains A1 fully (VMW(8) would be a no-op)
    const int pb = 65536;
    bf16x8 af[4], bv0[4], bv1[4];
    LDA(0, 0) LDB(bv0, 0) BAR; LGKM0; MFMA16(0, bv0) BAR;
    LDA(0, 1) LDB(bv1, 1) BAR; LGKM0; MFMA16(0, bv1) VMW(0); BAR;
    LDA(1, 0) BAR; LGKM0; MFMA16(1, bv0) BAR;
    LDA(1, 1) BAR; LGKM0; MFMA16(1, bv1)
  }

  // epilogue: D layout col=lane&15, row=quad*4+reg  [m89-verified]
  // remapped rows: acc[mi] -> grow = bm*256 + (mi>>2)*128 + wm*64 + (mi&3)*16 + quad*4 + r
  const int lc0 = bn * 256 + wn * 64 + fr;
  float be[4];
#pragma unroll
  for (int nj = 0; nj < 4; ++nj) be[nj] = b_enc[lc0 + nj * 16];
#pragma unroll
  for (int mi = 0; mi < 8; ++mi) {
#pragma unroll
    for (int r = 0; r < 4; ++r) {
      const int grow = bm * 256 + (mi >> 2) * 128 + wm * 64 + (mi & 3) * 16 + quad * 4 + r;
      const float thr = 2.3f * srow[grow];
#pragma unroll
      for (int nj = 0; nj < 4; ++nj) {
        const float val = acc[mi][nj][r] + be[nj];
        if (val > thr) {
          const int p = atomicAdd(&cand_cnt[grow * CNT_STRIDE], 1);
          if (p < CAP) {
            cand_val[(size_t)grow * CAP + p] = val;
            cand_idx[(size_t)grow * CAP + p] = lc0 + nj * 16;
          }
        }
      }
    }
  }
#undef GLD
#undef STGALL
#undef LDA
#undef LDB
#undef MFMA16
#undef BAR
#undef LGKM0
#undef VMW
}

// ---------------- select + fp64 refine + zero+scatter f + fused decode ----------------
__global__ __launch_bounds__(256) void select_decode(
    const float* __restrict__ x,
    const float* __restrict__ W_enc,
    const float* __restrict__ b_enc,
    const float* __restrict__ b_dec,
    const float* __restrict__ srow,
    const int* __restrict__ cand_cnt,
    const float* __restrict__ cand_val,
    const int* __restrict__ cand_idx,
    const unsigned short* __restrict__ WdTb,
    float* __restrict__ f,
    float* __restrict__ xhat) {
  const int b = blockIdx.x, t = threadIdx.x;
  const int lane = t & 63, wave = t >> 6;
  __shared__ double xd[D_N];       // exact xbar in fp64
  __shared__ float cv[CAP];
  __shared__ int ci[CAP];
  __shared__ double bu[128];       // boundary fp64 scores
  __shared__ int bidx[128];        // boundary slot -> cand slot
  __shared__ int o_idx[K_N];
  __shared__ float o_val[K_N];
  __shared__ int sidx[K_N];
  __shared__ float sval[K_N];
  __shared__ int nb_s, nin_s, outcnt;
  __shared__ float v64_s;

  // zero this row of f FIRST — fire-and-forget, overlaps everything below;
  // drained (vmcnt) + barrier-ordered before the sparse scatter at the end.
  {
    const float4 z4 = make_float4(0.f, 0.f, 0.f, 0.f);
    float4* frow = (float4*)(f + (size_t)b * L_N);
#pragma unroll
    for (int i = 0; i < 16; ++i) frow[i * 256 + t] = z4;   // 4096 float4 = 64 KB
  }

  const int cnt = min(cand_cnt[b * CNT_STRIDE], CAP);
  if (t == 0) { nb_s = 0; nin_s = 0; outcnt = 0; v64_s = -1e30f; }
  for (int c = t; c < cnt; c += 256) {
    cv[c] = cand_val[(size_t)b * CAP + c];
    ci[c] = cand_idx[(size_t)b * CAP + c];
  }
  for (int i = t; i < D_N; i += 256)
    xd[i] = (double)x[(size_t)b * D_N + i] - (double)b_dec[i];
  __syncthreads();

  // v64 = 64th-largest approx value (unique by (val, idx) lexicographic)
  for (int c = t; c < cnt; c += 256) {
    const float v = cv[c];
    const int id = ci[c];
    int r = 0;
    for (int k = 0; k < cnt; ++k)
      r += (cv[k] > v || (cv[k] == v && ci[k] < id)) ? 1 : 0;
    if (r == 63) v64_s = v;   // unique writer
  }
  __syncthreads();
  const float v64 = v64_s;
  const float m = 0.04f * srow[b];

  // classify: definite-in (v > v64+m), boundary (|v - v64| <= m)
  for (int c = t; c < cnt; c += 256) {
    const float v = cv[c];
    if (v > v64 + m) {
      atomicAdd(&nin_s, 1);
    } else if (v >= v64 - m) {
      const int p = atomicAdd(&nb_s, 1);
      if (p < 128) bidx[p] = c;
    }
  }
  __syncthreads();
  const int nb = min(nb_s, 128);
  const int nin = nin_s;
  int nneed = K_N - nin;
  if (nneed < 0) nneed = 0;

  // fp64 exact scores for boundary candidates (one wave per candidate)
  for (int c = wave; c < nb; c += 4) {
    const int l = ci[bidx[c]];
    const float4* wr = (const float4*)(W_enc + (size_t)l * D_N);
    double acc = 0.0;
#pragma unroll
    for (int j = 0; j < 4; ++j) {
      float4 w4 = wr[j * 64 + lane];
      const int base = (j * 64 + lane) * 4;
      acc += xd[base + 0] * (double)w4.x + xd[base + 1] * (double)w4.y +
             xd[base + 2] * (double)w4.z + xd[base + 3] * (double)w4.w;
    }
#pragma unroll
    for (int off = 32; off; off >>= 1) acc += __shfl_down(acc, off);
    if (lane == 0) bu[c] = acc + (double)b_enc[l];
  }
  __syncthreads();

  // emit definite-ins with approx values
  for (int c = t; c < cnt; c += 256) {
    if (cv[c] > v64 + m) {
      const int p = atomicAdd(&outcnt, 1);
      if (p < K_N) { o_idx[p] = ci[c]; o_val[p] = cv[c]; }
    }
  }
  // emit best nneed boundary candidates by exact fp64 score
  if (t < nb) {
    const double uv = bu[t];
    const int l = ci[bidx[t]];
    int r = 0;
    for (int k = 0; k < nb; ++k)
      r += (bu[k] > uv || (bu[k] == uv && ci[bidx[k]] < l)) ? 1 : 0;
    if (r < nneed) {
      const int p = atomicAdd(&outcnt, 1);
      if (p < K_N) { o_idx[p] = l; o_val[p] = (float)uv; }
    }
  }
  __syncthreads();
  const int ns = min(outcnt, K_N);

  if (t < K_N) {
    sidx[t] = (t < ns) ? o_idx[t] : t;
    sval[t] = (t < ns) ? fmaxf(o_val[t], 0.0f) : 0.0f;
  }
  // order the row-zero stores before the sparse scatter: each thread drains its
  // own stores to the coherence point, then barrier, then scatter.
  asm volatile("s_waitcnt vmcnt(0)" ::: "memory");
  __syncthreads();

  // scatter into f (row zeroed above)
  if (t < ns) f[(size_t)b * L_N + sidx[t]] = sval[t];

  // fused decode: xhat row = sum_k sval[k] * W_decT[sidx[k],:] + b_dec
  float4 acc = ((const float4*)b_dec)[t];   // 256 float4 == D_N
#pragma unroll 8
  for (int k = 0; k < K_N; ++k) {
    const float v = sval[k];
    const ushort4 w = ((const ushort4*)(WdTb + (size_t)sidx[k] * D_N))[t];
    acc.x += v * bf2f(w.x); acc.y += v * bf2f(w.y);
    acc.z += v * bf2f(w.z); acc.w += v * bf2f(w.w);
  }
  ((float4*)(xhat + (size_t)b * D_N))[t] = acc;
}

extern "C" void kernel_launch(void* const* d_in, const int* in_sizes, int n_in,
                              void* d_out, int out_size, void* d_ws, size_t ws_size,
                              hipStream_t stream) {
  (void)in_sizes; (void)n_in; (void)out_size; (void)ws_size;
  const float* x     = (const float*)d_in[0];   // [B][D]
  const float* W_enc = (const float*)d_in[1];   // [L][D]
  const float* b_enc = (const float*)d_in[2];   // [L]
  const float* W_dec = (const float*)d_in[3];   // [D][L]
  const float* b_dec = (const float*)d_in[4];   // [D]

  float* f    = (float*)d_out;                        // [B][L]
  float* xhat = (float*)d_out + (size_t)B_N * L_N;    // [B][D]

  // workspace layout (~92 MB total)
  char* ws = (char*)d_ws;
  unsigned short* wencb = (unsigned short*)ws;                   // 32 MB bf16 W_enc
  unsigned short* xbarb = (unsigned short*)(ws + 33554432);      //  8 MB bf16 xbar
  unsigned short* WdTb  = (unsigned short*)(ws + 41943040);      // 32 MB bf16 W_dec^T
  float* srow           = (float*)(ws + 75497472);               // 16 KB
  int* cand_cnt         = (int*)(ws + 75513856);                 // 256 KB (line-padded)
  float* cand_val       = (float*)(ws + 75776000);               //  8 MB
  int* cand_idx         = (int*)(ws + 84164608);                 //  8 MB

  prep_all<<<36864, 256, 0, stream>>>(x, W_enc, W_dec, b_dec, wencb, xbarb, srow,
                                      WdTb, cand_cnt);
  gemm_enc_select<<<1024, 512, 0, stream>>>(
      xbarb, wencb, b_enc, srow, cand_cnt, cand_val, cand_idx);
  select_decode<<<B_N, 256, 0, stream>>>(x, W_enc, b_enc, b_dec, srow,
                                         cand_cnt, cand_val, cand_idx, WdTb, f, xhat);
}

// Round 6
// 782.907 us; speedup vs baseline: 1.6571x; 1.0172x over previous
//
#include <hip/hip_runtime.h>

#define B_N 4096
#define D_N 1024
#define L_N 16384
#define K_N 64
#define CAP 512
#define CNT_STRIDE 16   // one cand counter per 64B cache line

typedef __attribute__((ext_vector_type(8))) short bf16x8;
typedef __attribute__((ext_vector_type(4))) float f32x4;

__device__ __forceinline__ unsigned short f2bf(float f) {
  union { float f; unsigned int u; } v; v.f = f;
  unsigned int r = v.u + 0x7FFFu + ((v.u >> 16) & 1u);
  return (unsigned short)(r >> 16);
}
__device__ __forceinline__ float bf2f(unsigned short u) {
  union { unsigned int u; float f; } v; v.u = (unsigned int)u << 16;
  return v.f;
}
__device__ __forceinline__ void nt_store4(float* p, float a, float b2, float c, float d) {
  f32x4 v = {a, b2, c, d};
  __builtin_nontemporal_store(v, (f32x4*)p);
}

// ---------------- prep 1/3: W_enc fp32 -> bf16 (grid-stride) ----------------
__global__ __launch_bounds__(256) void prep_wenc(const float* __restrict__ W_enc,
                                                 unsigned short* __restrict__ wencb) {
  const size_t n4 = (size_t)L_N * D_N / 4;            // 4M float4
  for (size_t i = (size_t)blockIdx.x * 256 + threadIdx.x; i < n4; i += (size_t)2048 * 256) {
    float4 v = ((const float4*)W_enc)[i];
    ushort4 o;
    o.x = f2bf(v.x); o.y = f2bf(v.y); o.z = f2bf(v.z); o.w = f2bf(v.w);
    ((ushort4*)wencb)[i] = o;
  }
}

// ---------------- prep 2/3: xbar bf16 + per-row sigma + cand_cnt zero ----------------
__global__ __launch_bounds__(256) void prep_xbar(const float* __restrict__ x,
                                                 const float* __restrict__ b_dec,
                                                 unsigned short* __restrict__ xbarb,
                                                 float* __restrict__ srow,
                                                 int* __restrict__ cand_cnt) {
  __shared__ float wsum[4];
  const int b = blockIdx.x, t = threadIdx.x;
  if (t == 0) cand_cnt[b * CNT_STRIDE] = 0;
  float4 v = ((const float4*)x)[(size_t)b * 256 + t];
  float4 bd = ((const float4*)b_dec)[t];
  float4 e = make_float4(v.x - bd.x, v.y - bd.y, v.z - bd.z, v.w - bd.w);
  ushort4 o;
  o.x = f2bf(e.x); o.y = f2bf(e.y); o.z = f2bf(e.z); o.w = f2bf(e.w);
  ((ushort4*)xbarb)[(size_t)b * 256 + t] = o;
  float ss = e.x * e.x + e.y * e.y + e.z * e.z + e.w * e.w;
#pragma unroll
  for (int off = 32; off; off >>= 1) ss += __shfl_down(ss, off);
  if ((t & 63) == 0) wsum[t >> 6] = ss;
  __syncthreads();
  if (t == 0) srow[b] = sqrtf((wsum[0] + wsum[1] + wsum[2] + wsum[3]) * (1.0f / D_N));
}

// ---------------- prep 3/3: W_dec [D][L] -> W_decT bf16 [L][D], 64x64 tiles ----------------
// Full-line global reads (256B rows) and 128B coalesced ushort4 writes (old
// version wrote 64B half-lines). LDS scalar ops, 2-way bank aliasing (free).
__global__ __launch_bounds__(256) void prep_wdt(const float* __restrict__ W_dec,
                                                unsigned short* __restrict__ WdTb) {
  __shared__ float tile[64][65];
  const int t = threadIdx.x;
  const int l0 = (blockIdx.x >> 4) << 6;   // 256 l-tiles
  const int d0 = (blockIdx.x & 15) << 6;   // 16 d-tiles
  {
    const int c4 = (t & 15) * 4;
    const int r0 = t >> 4;
#pragma unroll
    for (int p = 0; p < 4; ++p) {
      const int r = r0 + p * 16;
      float4 v = *(const float4*)&W_dec[(size_t)(d0 + r) * L_N + l0 + c4];
      tile[r][c4 + 0] = v.x; tile[r][c4 + 1] = v.y;
      tile[r][c4 + 2] = v.z; tile[r][c4 + 3] = v.w;
    }
  }
  __syncthreads();
  {
    const int j4 = (t & 15) * 4;           // d within tile
    const int i0 = t >> 4;                 // l within tile
#pragma unroll
    for (int p = 0; p < 4; ++p) {
      const int i = i0 + p * 16;
      ushort4 o;
      o.x = f2bf(tile[j4 + 0][i]); o.y = f2bf(tile[j4 + 1][i]);
      o.z = f2bf(tile[j4 + 2][i]); o.w = f2bf(tile[j4 + 3][i]);
      *(ushort4*)&WdTb[(size_t)(l0 + i) * D_N + d0 + j4] = o;
    }
  }
}

// ---------------- encoder GEMM 256x256, BK=64, 8 waves, dbuf 128KB, deep counted-vmcnt ----
// (R5 kernel, unchanged — best measured variant: 271.8 us, conflicts 0.)
__global__ __launch_bounds__(512, 2) void gemm_enc_select(
    const unsigned short* __restrict__ A,   // xbar bf16 [B][D]
    const unsigned short* __restrict__ Bw,  // W_enc bf16 [L][D]
    const float* __restrict__ b_enc,
    const float* __restrict__ srow,
    int* __restrict__ cand_cnt,             // [B] stride CNT_STRIDE
    float* __restrict__ cand_val,           // [B][CAP]
    int* __restrict__ cand_idx) {           // [B][CAP]
  __shared__ __align__(16) char smem[131072];  // buf p @ p*65536: A[256][64] @0, B @32768
  const int tid = threadIdx.x;
  const int wid = tid >> 6, lane = tid & 63;
  const int wm = wid >> 2, wn = wid & 3;    // 2 x 4 wave grid
  const int fr = lane & 15, quad = lane >> 4;

  // bijective XCD swizzle: 1024 blocks, 1024 % 8 == 0
  const int wg = ((blockIdx.x & 7) << 7) + (blockIdx.x >> 3);
  const int bm = wg & 15, bn = wg >> 4;     // 16 x 64 tiles

  const int stgrow = wid * 8 + (lane >> 3);
  const int scol = ((lane & 7) ^ (lane >> 3)) << 4;
  const char* gA = (const char*)A + ((size_t)(bm * 256 + stgrow) * D_N) * 2 + scol;
  const char* gB = (const char*)Bw + ((size_t)(bn * 256 + stgrow) * D_N) * 2 + scol;

#define GLD(src_, dst_)                                                   \
  __builtin_amdgcn_global_load_lds(                                       \
      (const __attribute__((address_space(1))) void*)(src_),              \
      (__attribute__((address_space(3))) void*)(dst_), 16, 0, 0)

#define STGALL(po_, ko_)                                                              \
  {                                                                                   \
    _Pragma("unroll") for (int r_ = 0; r_ < 4; ++r_)                                  \
        GLD(gB + (size_t)r_ * 131072 + (ko_), smem + (po_) + 32768 + r_ * 8192 + wid * 1024); \
    _Pragma("unroll") for (int r_ = 0; r_ < 4; ++r_)                                  \
        GLD(gA + (size_t)r_ * 131072 + (ko_), smem + (po_) + r_ * 8192 + wid * 1024); \
  }

#define LDA(rh_, ks_)                                                                 \
  _Pragma("unroll") for (int i_ = 0; i_ < 4; ++i_)                                    \
      af[i_] = *(const bf16x8*)(smem + pb + (rh_)*16384 + aB + i_ * 2048 + (s0 ^ ((ks_)*64)));

#define LDB(dst_, ks_)                                                                \
  _Pragma("unroll") for (int j_ = 0; j_ < 4; ++j_)                                    \
      dst_[j_] = *(const bf16x8*)(smem + pb + bB + j_ * 2048 + (s0 ^ ((ks_)*64)));

#define MFMA16(rh_, bv_)                                                              \
  __builtin_amdgcn_s_setprio(1);                                                      \
  _Pragma("unroll") for (int i_ = 0; i_ < 4; ++i_)                                    \
      _Pragma("unroll") for (int j_ = 0; j_ < 4; ++j_)                                \
          acc[(rh_)*4 + i_][j_] = __builtin_amdgcn_mfma_f32_16x16x32_bf16(            \
              af[i_], bv_[j_], acc[(rh_)*4 + i_][j_], 0, 0, 0);                       \
  __builtin_amdgcn_s_setprio(0);

#define BAR __builtin_amdgcn_s_barrier()
#define LGKM0                                                                         \
  do {                                                                                \
    asm volatile("s_waitcnt lgkmcnt(0)" ::: "memory");                                \
    __builtin_amdgcn_sched_barrier(0);                                                \
  } while (0)
#define VMW(n_) asm volatile("s_waitcnt vmcnt(" #n_ ")" ::: "memory")

  f32x4 acc[8][4];
#pragma unroll
  for (int i = 0; i < 8; ++i)
#pragma unroll
    for (int j = 0; j < 4; ++j) acc[i][j] = (f32x4){0.f, 0.f, 0.f, 0.f};

  const int aB = (wm * 64 + fr) * 128;
  const int bB = 32768 + (wn * 64 + fr) * 128;
  const int s0 = (quad ^ (fr & 7)) << 4;

  STGALL(0, (size_t)0)
  VMW(2);
  BAR;

  for (int kt = 0; kt < 15; ++kt) {
    const int pb = (kt & 1) * 65536;
    const int po = pb ^ 65536;
    const size_t ko = (size_t)(kt + 1) * 128;
    bf16x8 af[4], bv0[4], bv1[4];
    LDA(0, 0) LDB(bv0, 0) STGALL(po, ko) BAR; LGKM0; MFMA16(0, bv0) BAR;
    LDA(0, 1) LDB(bv1, 1) BAR; LGKM0; MFMA16(0, bv1) VMW(8); BAR;
    LDA(1, 0) BAR; LGKM0; MFMA16(1, bv0) VMW(2); BAR;
    LDA(1, 1) BAR; LGKM0; MFMA16(1, bv1) BAR;
  }
  {
    const int pb = 65536;
    bf16x8 af[4], bv0[4], bv1[4];
    LDA(0, 0) LDB(bv0, 0) BAR; LGKM0; MFMA16(0, bv0) BAR;
    LDA(0, 1) LDB(bv1, 1) BAR; LGKM0; MFMA16(0, bv1) VMW(0); BAR;
    LDA(1, 0) BAR; LGKM0; MFMA16(1, bv0) BAR;
    LDA(1, 1) BAR; LGKM0; MFMA16(1, bv1)
  }

  // epilogue: D layout col=lane&15, row=quad*4+reg  [m89-verified]
  const int lc0 = bn * 256 + wn * 64 + fr;
  float be[4];
#pragma unroll
  for (int nj = 0; nj < 4; ++nj) be[nj] = b_enc[lc0 + nj * 16];
#pragma unroll
  for (int mi = 0; mi < 8; ++mi) {
#pragma unroll
    for (int r = 0; r < 4; ++r) {
      const int grow = bm * 256 + (mi >> 2) * 128 + wm * 64 + (mi & 3) * 16 + quad * 4 + r;
      const float thr = 2.3f * srow[grow];
#pragma unroll
      for (int nj = 0; nj < 4; ++nj) {
        const float val = acc[mi][nj][r] + be[nj];
        if (val > thr) {
          const int p = atomicAdd(&cand_cnt[grow * CNT_STRIDE], 1);
          if (p < CAP) {
            cand_val[(size_t)grow * CAP + p] = val;
            cand_idx[(size_t)grow * CAP + p] = lc0 + nj * 16;
          }
        }
      }
    }
  }
#undef GLD
#undef STGALL
#undef LDA
#undef LDB
#undef MFMA16
#undef BAR
#undef LGKM0
#undef VMW
}

// ---------------- select + fp64 refine + zero+scatter f + fused decode ----------------
// Streaming outputs (f zero-fill, xhat) now use nontemporal stores so the
// 320 MB of write-allocates stop evicting W_enc / WdTb from L2/LLC (the
// refine + decode gather reads are the kernel's dominant traffic).
__global__ __launch_bounds__(256) void select_decode(
    const float* __restrict__ x,
    const float* __restrict__ W_enc,
    const float* __restrict__ b_enc,
    const float* __restrict__ b_dec,
    const float* __restrict__ srow,
    const int* __restrict__ cand_cnt,
    const float* __restrict__ cand_val,
    const int* __restrict__ cand_idx,
    const unsigned short* __restrict__ WdTb,
    float* __restrict__ f,
    float* __restrict__ xhat) {
  const int b = blockIdx.x, t = threadIdx.x;
  const int lane = t & 63, wave = t >> 6;
  __shared__ double xd[D_N];       // exact xbar in fp64
  __shared__ float cv[CAP];
  __shared__ int ci[CAP];
  __shared__ double bu[128];       // boundary fp64 scores
  __shared__ int bidx[128];        // boundary slot -> cand slot
  __shared__ int o_idx[K_N];
  __shared__ float o_val[K_N];
  __shared__ int sidx[K_N];
  __shared__ float sval[K_N];
  __shared__ int nb_s, nin_s, outcnt;
  __shared__ float v64_s;

  // zero this row of f FIRST — nontemporal fire-and-forget; drained (vmcnt)
  // + barrier-ordered before the sparse scatter at the end.
  {
    float* frow = f + (size_t)b * L_N;
#pragma unroll
    for (int i = 0; i < 16; ++i)
      nt_store4(frow + (i * 256 + t) * 4, 0.f, 0.f, 0.f, 0.f);
  }

  const int cnt = min(cand_cnt[b * CNT_STRIDE], CAP);
  if (t == 0) { nb_s = 0; nin_s = 0; outcnt = 0; v64_s = -1e30f; }
  for (int c = t; c < cnt; c += 256) {
    cv[c] = cand_val[(size_t)b * CAP + c];
    ci[c] = cand_idx[(size_t)b * CAP + c];
  }
  for (int i = t; i < D_N; i += 256)
    xd[i] = (double)x[(size_t)b * D_N + i] - (double)b_dec[i];
  __syncthreads();

  // v64 = 64th-largest approx value (unique by (val, idx) lexicographic)
  for (int c = t; c < cnt; c += 256) {
    const float v = cv[c];
    const int id = ci[c];
    int r = 0;
    for (int k = 0; k < cnt; ++k)
      r += (cv[k] > v || (cv[k] == v && ci[k] < id)) ? 1 : 0;
    if (r == 63) v64_s = v;   // unique writer
  }
  __syncthreads();
  const float v64 = v64_s;
  const float m = 0.04f * srow[b];

  // classify: definite-in (v > v64+m), boundary (|v - v64| <= m)
  for (int c = t; c < cnt; c += 256) {
    const float v = cv[c];
    if (v > v64 + m) {
      atomicAdd(&nin_s, 1);
    } else if (v >= v64 - m) {
      const int p = atomicAdd(&nb_s, 1);
      if (p < 128) bidx[p] = c;
    }
  }
  __syncthreads();
  const int nb = min(nb_s, 128);
  const int nin = nin_s;
  int nneed = K_N - nin;
  if (nneed < 0) nneed = 0;

  // fp64 exact scores for boundary candidates (one wave per candidate)
  for (int c = wave; c < nb; c += 4) {
    const int l = ci[bidx[c]];
    const float4* wr = (const float4*)(W_enc + (size_t)l * D_N);
    double acc = 0.0;
#pragma unroll
    for (int j = 0; j < 4; ++j) {
      float4 w4 = wr[j * 64 + lane];
      const int base = (j * 64 + lane) * 4;
      acc += xd[base + 0] * (double)w4.x + xd[base + 1] * (double)w4.y +
             xd[base + 2] * (double)w4.z + xd[base + 3] * (double)w4.w;
    }
#pragma unroll
    for (int off = 32; off; off >>= 1) acc += __shfl_down(acc, off);
    if (lane == 0) bu[c] = acc + (double)b_enc[l];
  }
  __syncthreads();

  // emit definite-ins with approx values
  for (int c = t; c < cnt; c += 256) {
    if (cv[c] > v64 + m) {
      const int p = atomicAdd(&outcnt, 1);
      if (p < K_N) { o_idx[p] = ci[c]; o_val[p] = cv[c]; }
    }
  }
  // emit best nneed boundary candidates by exact fp64 score
  if (t < nb) {
    const double uv = bu[t];
    const int l = ci[bidx[t]];
    int r = 0;
    for (int k = 0; k < nb; ++k)
      r += (bu[k] > uv || (bu[k] == uv && ci[bidx[k]] < l)) ? 1 : 0;
    if (r < nneed) {
      const int p = atomicAdd(&outcnt, 1);
      if (p < K_N) { o_idx[p] = l; o_val[p] = (float)uv; }
    }
  }
  __syncthreads();
  const int ns = min(outcnt, K_N);

  if (t < K_N) {
    sidx[t] = (t < ns) ? o_idx[t] : t;
    sval[t] = (t < ns) ? fmaxf(o_val[t], 0.0f) : 0.0f;
  }
  // order the row-zero stores before the sparse scatter
  asm volatile("s_waitcnt vmcnt(0)" ::: "memory");
  __syncthreads();

  // scatter into f (row zeroed above)
  if (t < ns) f[(size_t)b * L_N + sidx[t]] = sval[t];

  // fused decode: xhat row = sum_k sval[k] * W_decT[sidx[k],:] + b_dec
  float4 acc = ((const float4*)b_dec)[t];   // 256 float4 == D_N
#pragma unroll 8
  for (int k = 0; k < K_N; ++k) {
    const float v = sval[k];
    const ushort4 w = ((const ushort4*)(WdTb + (size_t)sidx[k] * D_N))[t];
    acc.x += v * bf2f(w.x); acc.y += v * bf2f(w.y);
    acc.z += v * bf2f(w.z); acc.w += v * bf2f(w.w);
  }
  nt_store4(xhat + (size_t)b * D_N + t * 4, acc.x, acc.y, acc.z, acc.w);
}

extern "C" void kernel_launch(void* const* d_in, const int* in_sizes, int n_in,
                              void* d_out, int out_size, void* d_ws, size_t ws_size,
                              hipStream_t stream) {
  (void)in_sizes; (void)n_in; (void)out_size; (void)ws_size;
  const float* x     = (const float*)d_in[0];   // [B][D]
  const float* W_enc = (const float*)d_in[1];   // [L][D]
  const float* b_enc = (const float*)d_in[2];   // [L]
  const float* W_dec = (const float*)d_in[3];   // [D][L]
  const float* b_dec = (const float*)d_in[4];   // [D]

  float* f    = (float*)d_out;                        // [B][L]
  float* xhat = (float*)d_out + (size_t)B_N * L_N;    // [B][D]

  // workspace layout (~92 MB total)
  char* ws = (char*)d_ws;
  unsigned short* wencb = (unsigned short*)ws;                   // 32 MB bf16 W_enc
  unsigned short* xbarb = (unsigned short*)(ws + 33554432);      //  8 MB bf16 xbar
  unsigned short* WdTb  = (unsigned short*)(ws + 41943040);      // 32 MB bf16 W_dec^T
  float* srow           = (float*)(ws + 75497472);               // 16 KB
  int* cand_cnt         = (int*)(ws + 75513856);                 // 256 KB (line-padded)
  float* cand_val       = (float*)(ws + 75776000);               //  8 MB
  int* cand_idx         = (int*)(ws + 84164608);                 //  8 MB

  prep_wenc<<<2048, 256, 0, stream>>>(W_enc, wencb);
  prep_xbar<<<4096, 256, 0, stream>>>(x, b_dec, xbarb, srow, cand_cnt);
  gemm_enc_select<<<1024, 512, 0, stream>>>(
      xbarb, wencb, b_enc, srow, cand_cnt, cand_val, cand_idx);
  prep_wdt<<<4096, 256, 0, stream>>>(W_dec, WdTb);
  select_decode<<<B_N, 256, 0, stream>>>(x, W_enc, b_enc, b_dec, srow,
                                         cand_cnt, cand_val, cand_idx, WdTb, f, xhat);
}